// Round 2
// baseline (20049.452 us; speedup 1.0000x reference)
//
#include <hip/hip_runtime.h>
#include <hip/hip_bf16.h>
#include <math.h>

typedef __hip_bfloat16 bf16;

#define Bb   4
#define Ss   512
#define Dd   768
#define Hh   12
#define Ll   12
#define Ff   3072
#define DHh  64
#define Pp   512
#define BSs  (Bb*Ss)
#define BHh  (Bb*Hh)

// adaptive float load: isb=1 -> buffer is bf16, isb=0 -> fp32
__device__ __forceinline__ float ldf(const void* p, long i, int isb){
  return isb ? __bfloat162float(((const bf16*)p)[i]) : ((const float*)p)[i];
}

// dtype sniff: attention_mask is all ones. packed bf16 ones = 0x3F803F80.
__global__ void sniff_kernel(const unsigned* __restrict__ mask_raw, int* __restrict__ flag){
  if (threadIdx.x == 0 && blockIdx.x == 0)
    *flag = (mask_raw[0] == 0x3F803F80u) ? 1 : 0;
}

// ---------------- reductions (256-thread block = 4 waves) ----------------
__device__ __forceinline__ float wave_sum(float v){
  #pragma unroll
  for (int o = 32; o > 0; o >>= 1) v += __shfl_down(v, o, 64);
  return v;
}
__device__ __forceinline__ float wave_max(float v){
  #pragma unroll
  for (int o = 32; o > 0; o >>= 1) v = fmaxf(v, __shfl_down(v, o, 64));
  return v;
}
__device__ __forceinline__ float block_sum(float v, float* red){
  v = wave_sum(v);
  if ((threadIdx.x & 63) == 0) red[threadIdx.x >> 6] = v;
  __syncthreads();
  float r = red[0] + red[1] + red[2] + red[3];
  __syncthreads();
  return r;
}
__device__ __forceinline__ float block_max(float v, float* red){
  v = wave_max(v);
  if ((threadIdx.x & 63) == 0) red[threadIdx.x >> 6] = v;
  __syncthreads();
  float r = fmaxf(fmaxf(red[0], red[1]), fmaxf(red[2], red[3]));
  __syncthreads();
  return r;
}

// ---------------- batched f32 GEMM (attention): C = A @ B, per-head offsets ----
// A: [M,K] (lda). B: TRB ? [N,K] : [K,N] (ldb). C: [M,N] (ldc). blockIdx.z = head.
template<bool TRB>
__global__ __launch_bounds__(256)
void gemm_f32_kernel(const float* __restrict__ A, const float* __restrict__ Bm,
                     float* __restrict__ C, int M, int N, int K,
                     int lda, int ldb, int ldc,
                     long offAh, long offBh, long offCh)
{
  int hh = blockIdx.z;
  A  += hh*offAh;
  Bm += hh*offBh;
  C  += hh*offCh;

  __shared__ __align__(16) float As[16][68];
  __shared__ __align__(16) float Bs[16][68];
  const int tid = threadIdx.x;
  const int tx = tid & 15, ty = tid >> 4;
  const int row0 = blockIdx.y * 64, col0 = blockIdx.x * 64;
  float acc[4][4] = {};

  for (int k0 = 0; k0 < K; k0 += 16) {
    #pragma unroll
    for (int i = 0; i < 4; i++) {
      int e = i*256 + tid;
      int m = e >> 4, kk = e & 15;
      As[kk][m] = A[(long)(row0+m)*lda + (k0+kk)];
    }
    #pragma unroll
    for (int i = 0; i < 4; i++) {
      int e = i*256 + tid;
      if (!TRB) { int n = e & 63, kk = e >> 6; Bs[kk][n] = Bm[(long)(k0+kk)*ldb + (col0+n)]; }
      else      { int n = e >> 4, kk = e & 15; Bs[kk][n] = Bm[(long)(col0+n)*ldb + (k0+kk)]; }
    }
    __syncthreads();
    #pragma unroll
    for (int kk = 0; kk < 16; kk++) {
      float4 a4 = *(const float4*)&As[kk][ty*4];
      float4 b4 = *(const float4*)&Bs[kk][tx*4];
      acc[0][0] += a4.x*b4.x; acc[0][1] += a4.x*b4.y; acc[0][2] += a4.x*b4.z; acc[0][3] += a4.x*b4.w;
      acc[1][0] += a4.y*b4.x; acc[1][1] += a4.y*b4.y; acc[1][2] += a4.y*b4.z; acc[1][3] += a4.y*b4.w;
      acc[2][0] += a4.z*b4.x; acc[2][1] += a4.z*b4.y; acc[2][2] += a4.z*b4.z; acc[2][3] += a4.z*b4.w;
      acc[3][0] += a4.w*b4.x; acc[3][1] += a4.w*b4.y; acc[3][2] += a4.w*b4.z; acc[3][3] += a4.w*b4.w;
    }
    __syncthreads();
  }

  #pragma unroll
  for (int i = 0; i < 4; i++) {
    int r = row0 + ty*4 + i;
    #pragma unroll
    for (int j = 0; j < 4; j++) {
      int c = col0 + tx*4 + j;
      C[(long)r*ldc + c] = acc[i][j];
    }
  }
}

// ---------------- weight GEMM: C = A @ W[woff..] + bias[obias..] ----------------
// W logical [K,N] row-major, raw input buffer (dtype per flag). EPI 1 = exact gelu.
template<int EPI>
__global__ __launch_bounds__(256)
void gemm_w_kernel(const float* __restrict__ A, const void* __restrict__ W,
                   const void* __restrict__ bias, float* __restrict__ C,
                   int M, int N, int K, long woff, long obias,
                   const int* __restrict__ flag)
{
  const int isb = *flag;
  __shared__ __align__(16) float As[16][68];
  __shared__ __align__(16) float Bs[16][68];
  const int tid = threadIdx.x;
  const int tx = tid & 15, ty = tid >> 4;
  const int row0 = blockIdx.y * 64, col0 = blockIdx.x * 64;
  float acc[4][4] = {};

  for (int k0 = 0; k0 < K; k0 += 16) {
    #pragma unroll
    for (int i = 0; i < 4; i++) {
      int e = i*256 + tid;
      int m = e >> 4, kk = e & 15;
      As[kk][m] = A[(long)(row0+m)*K + (k0+kk)];
    }
    #pragma unroll
    for (int i = 0; i < 4; i++) {
      int e = i*256 + tid;
      int n = e & 63, kk = e >> 6;
      Bs[kk][n] = ldf(W, woff + (long)(k0+kk)*N + (col0+n), isb);
    }
    __syncthreads();
    #pragma unroll
    for (int kk = 0; kk < 16; kk++) {
      float4 a4 = *(const float4*)&As[kk][ty*4];
      float4 b4 = *(const float4*)&Bs[kk][tx*4];
      acc[0][0] += a4.x*b4.x; acc[0][1] += a4.x*b4.y; acc[0][2] += a4.x*b4.z; acc[0][3] += a4.x*b4.w;
      acc[1][0] += a4.y*b4.x; acc[1][1] += a4.y*b4.y; acc[1][2] += a4.y*b4.z; acc[1][3] += a4.y*b4.w;
      acc[2][0] += a4.z*b4.x; acc[2][1] += a4.z*b4.y; acc[2][2] += a4.z*b4.z; acc[2][3] += a4.z*b4.w;
      acc[3][0] += a4.w*b4.x; acc[3][1] += a4.w*b4.y; acc[3][2] += a4.w*b4.z; acc[3][3] += a4.w*b4.w;
    }
    __syncthreads();
  }

  #pragma unroll
  for (int i = 0; i < 4; i++) {
    int r = row0 + ty*4 + i;
    #pragma unroll
    for (int j = 0; j < 4; j++) {
      int c = col0 + tx*4 + j;
      float v = acc[i][j] + ldf(bias, obias + c, isb);
      if (EPI == 1) v = 0.5f * v * (1.0f + erff(v * 0.70710678118654752f));
      C[(long)r*N + c] = v;
    }
  }
}

// ---------------- embedding + LN + mask ----------------
__global__ __launch_bounds__(256)
void embed_ln_kernel(const int* __restrict__ ids, const int* __restrict__ segs,
                     const int* __restrict__ pins, const void* __restrict__ mask,
                     const void* __restrict__ tok, const void* __restrict__ pin,
                     const void* __restrict__ seg, const void* __restrict__ lnw,
                     const void* __restrict__ lnb, float* __restrict__ h,
                     float* __restrict__ maskadd, const int* __restrict__ flag)
{
  __shared__ float red[4];
  const int isb = *flag;
  int t = blockIdx.x;
  long to = (long)ids[t]*Dd, po = (long)pins[t]*Dd, so = (long)segs[t]*Dd;
  float e[3]; float s = 0.f;
  #pragma unroll
  for (int i = 0; i < 3; i++) {
    int d = threadIdx.x + i*256;
    e[i] = ldf(tok, to+d, isb) + ldf(pin, po+d, isb) + ldf(seg, so+d, isb);
    s += e[i];
  }
  float mu = block_sum(s, red) * (1.0f/Dd);
  float vs = 0.f;
  #pragma unroll
  for (int i = 0; i < 3; i++) { float d0 = e[i]-mu; vs += d0*d0; }
  float var = block_sum(vs, red) * (1.0f/Dd);
  float inv = 1.0f / sqrtf(var + 1e-12f);
  float mv = ldf(mask, t, isb);
  #pragma unroll
  for (int i = 0; i < 3; i++) {
    int d = threadIdx.x + i*256;
    h[(long)t*Dd + d] = ((e[i]-mu)*inv*ldf(lnw, d, isb) + ldf(lnb, d, isb)) * mv;
  }
  if (threadIdx.x == 0) maskadd[t] = (1.0f - mv) * (-1e9f);
}

// ---------------- residual add + LN (in place, LN params at element offset) ----
__global__ __launch_bounds__(256)
void add_ln_kernel(float* __restrict__ h, const float* __restrict__ addv,
                   const void* __restrict__ w, const void* __restrict__ b,
                   long off, const int* __restrict__ flag)
{
  __shared__ float red[4];
  const int isb = *flag;
  int t = blockIdx.x;
  float e[3]; float s = 0.f;
  #pragma unroll
  for (int i = 0; i < 3; i++) {
    int d = threadIdx.x + i*256;
    e[i] = h[(long)t*Dd + d] + addv[(long)t*Dd + d];
    s += e[i];
  }
  float mu = block_sum(s, red) * (1.0f/Dd);
  float vs = 0.f;
  #pragma unroll
  for (int i = 0; i < 3; i++) { float d0 = e[i]-mu; vs += d0*d0; }
  float var = block_sum(vs, red) * (1.0f/Dd);
  float inv = 1.0f / sqrtf(var + 1e-12f);
  #pragma unroll
  for (int i = 0; i < 3; i++) {
    int d = threadIdx.x + i*256;
    h[(long)t*Dd + d] = (e[i]-mu)*inv*ldf(w, off+d, isb) + ldf(b, off+d, isb);
  }
}

// ---------------- DeBERTa-v2 log-bucket relative position indices ----------------
__global__ void relidx_kernel(int* __restrict__ cidx, int* __restrict__ pidx)
{
  int idx = blockIdx.x*256 + threadIdx.x;
  if (idx >= Ss*Ss) return;
  int r = idx / Ss, c = idx % Ss;
  int rel = r - c;
  const int mid = 128;
  int sgn = (rel > 0) - (rel < 0);
  int abs_pos = (rel < mid && rel > -mid) ? (mid - 1) : abs(rel);
  int bucket;
  if (abs_pos <= mid) bucket = rel;
  else {
    double lp = ceil(log((double)abs_pos / (double)mid) / log(511.0/128.0) * (double)(mid-1)) + (double)mid;
    bucket = (int)(lp * (double)sgn);
  }
  int ci = bucket + 256;  ci = ci < 0 ? 0 : (ci > 511 ? 511 : ci);
  int pi = -bucket + 256; pi = pi < 0 ? 0 : (pi > 511 ? 511 : pi);
  cidx[idx] = ci;   // cidx[q][k] = clip(bucket(q-k)+256)
  pidx[idx] = pi;   // pidx[k][q] = clip(-bucket(k-q)+256), stored [r=k][c=q]
}

// ---------------- qk + c2p-gather + p2c-gather + mask + softmax (one batch) ----
__global__ __launch_bounds__(256)
void attn_softmax_kernel(float* __restrict__ score, const float* __restrict__ c2p,
                         const float* __restrict__ p2c, const int* __restrict__ cidx,
                         const int* __restrict__ pidx, const float* __restrict__ maskadd)
{
  __shared__ float red[4];
  const float SCALE = 0.07216878364870322f;   // 1/sqrt(64*3)
  int q = blockIdx.x;
  int hd = blockIdx.y;
  float* row = score + ((long)hd*Ss + q)*Ss;
  const float* c2pr = c2p + (long)hd*Ss*Pp + (long)q*Pp;
  const float* p2cm = p2c + (long)hd*Ss*Pp;
  float v[2];
  #pragma unroll
  for (int i = 0; i < 2; i++) {
    int k = threadIdx.x + i*256;
    float sv = row[k] + c2pr[cidx[q*Ss + k]] + p2cm[(long)k*Pp + pidx[k*Ss + q]];
    v[i] = sv * SCALE + maskadd[k];
  }
  float mx = block_max(fmaxf(v[0], v[1]), red);
  float e0 = __expf(v[0] - mx), e1 = __expf(v[1] - mx);
  float inv = 1.0f / block_sum(e0 + e1, red);
  row[threadIdx.x]       = e0 * inv;
  row[threadIdx.x + 256] = e1 * inv;
}

// ---------------- converts ----------------
__global__ void cvt_in_kernel(const void* __restrict__ in, float* __restrict__ out,
                              const int* __restrict__ flag, int n){
  int i = blockIdx.x*256 + threadIdx.x;
  if (i < n) out[i] = ldf(in, i, *flag);
}
__global__ void store_out_kernel(const float* __restrict__ in, void* __restrict__ out,
                                 const int* __restrict__ flag, int n){
  int i = blockIdx.x*256 + threadIdx.x;
  if (i < n) {
    if (*flag) ((bf16*)out)[i] = __float2bfloat16(in[i]);
    else       ((float*)out)[i] = in[i];
  }
}

extern "C" void kernel_launch(void* const* d_in, const int* in_sizes, int n_in,
                              void* d_out, int out_size, void* d_ws, size_t ws_size,
                              hipStream_t stream)
{
  const int*  input_ids   = (const int*) d_in[0];
  const int*  segment_ids = (const int*) d_in[1];
  const int*  pinyin_ids  = (const int*) d_in[2];
  const void* attn_mask   = d_in[3];
  const void* tok_emb     = d_in[4];
  const void* pin_emb     = d_in[5];
  const void* seg_emb     = d_in[6];
  const void* emb_ln_w    = d_in[7];
  const void* emb_ln_b    = d_in[8];
  const void* rel_emb     = d_in[9];
  const void* Wq = d_in[10]; const void* bq = d_in[11];
  const void* Wk = d_in[12]; const void* bk = d_in[13];
  const void* Wv = d_in[14]; const void* bv = d_in[15];
  const void* Wo = d_in[16]; const void* bo = d_in[17];
  const void* ln1w = d_in[18]; const void* ln1b = d_in[19];
  const void* W1 = d_in[20]; const void* b1 = d_in[21];
  const void* W2 = d_in[22]; const void* b2 = d_in[23];
  const void* ln2w = d_in[24]; const void* ln2b = d_in[25];

  // ---- workspace layout (fp32 elements), total ~76 MB ----
  float* ws   = (float*)d_ws;
  float* h    = ws;                          // 2048*768
  float* kb   = h    + (long)BSs*Dd;
  float* vb   = kb   + (long)BSs*Dd;
  float* ctxb = vb   + (long)BSs*Dd;
  float* qb   = ctxb + (long)BSs*Dd;         // aliased as tmp after attention
  float* relf = qb   + (long)BSs*Dd;         // 512*768
  float* posk = relf + (long)Pp*Dd;
  float* posq = posk + (long)Pp*Dd;
  float* madd = posq + (long)Pp*Dd;          // 2048
  int*   cidx = (int*)(madd + BSs);          // 512*512
  int*   pidx = cidx + Ss*Ss;
  int*   dflag= pidx + Ss*Ss;                // 64 ints (alignment slack)
  float* scr  = (float*)(dflag + 64);        // 12*512*512 per-batch scores/probs
  float* c2pb = scr  + (long)Hh*Ss*Ss;       // 12*512*512
  float* p2cb = c2pb + (long)Hh*Ss*Pp;       // 12*512*512
  float* tmp  = qb;                          // alias: qb dead after c2p GEMMs
  float* ffb  = scr;                         // alias: spans scr+c2pb, dead in FFN

  sniff_kernel<<<1, 64, 0, stream>>>((const unsigned*)attn_mask, dflag);
  relidx_kernel<<<(Ss*Ss + 255)/256, 256, 0, stream>>>(cidx, pidx);
  cvt_in_kernel<<<(Pp*Dd + 255)/256, 256, 0, stream>>>(rel_emb, relf, dflag, Pp*Dd);
  embed_ln_kernel<<<BSs, 256, 0, stream>>>(input_ids, segment_ids, pinyin_ids, attn_mask,
                                           tok_emb, pin_emb, seg_emb, emb_ln_w, emb_ln_b,
                                           h, madd, dflag);

  dim3 gq(Dd/64, BSs/64, 1);     // [2048 x 768]
  dim3 gp(Dd/64, Pp/64, 1);      // [512 x 768]
  dim3 gf1(Ff/64, BSs/64, 1);    // [2048 x 3072]

  for (int l = 0; l < Ll; l++) {
    long oW  = (long)l*Dd*Dd, ob = (long)l*Dd;
    long oW1 = (long)l*Dd*Ff, ob1 = (long)l*Ff;
    long oW2 = (long)l*Ff*Dd;

    gemm_w_kernel<0><<<gq,256,0,stream>>>(h,    Wq, bq, qb,   BSs, Dd, Dd, oW, ob, dflag);
    gemm_w_kernel<0><<<gq,256,0,stream>>>(h,    Wk, bk, kb,   BSs, Dd, Dd, oW, ob, dflag);
    gemm_w_kernel<0><<<gq,256,0,stream>>>(h,    Wv, bv, vb,   BSs, Dd, Dd, oW, ob, dflag);
    gemm_w_kernel<0><<<gp,256,0,stream>>>(relf, Wk, bk, posk, Pp,  Dd, Dd, oW, ob, dflag);
    gemm_w_kernel<0><<<gp,256,0,stream>>>(relf, Wq, bq, posq, Pp,  Dd, Dd, oW, ob, dflag);

    for (int b = 0; b < Bb; b++) {
      const float* qbb = qb + (long)b*Ss*Dd;
      const float* kbb = kb + (long)b*Ss*Dd;
      // scores = Q @ K^T, per head
      gemm_f32_kernel<true><<<dim3(Ss/64,Ss/64,Hh),256,0,stream>>>(
          qbb, kbb, scr, Ss, Ss, DHh, Dd, Dd, Ss, 64L, 64L, (long)Ss*Ss);
      // c2p = Q @ pos_k^T
      gemm_f32_kernel<true><<<dim3(Pp/64,Ss/64,Hh),256,0,stream>>>(
          qbb, posk, c2pb, Ss, Pp, DHh, Dd, Dd, Pp, 64L, 64L, (long)Ss*Pp);
      // p2c = K @ pos_q^T
      gemm_f32_kernel<true><<<dim3(Pp/64,Ss/64,Hh),256,0,stream>>>(
          kbb, posq, p2cb, Ss, Pp, DHh, Dd, Dd, Pp, 64L, 64L, (long)Ss*Pp);
      attn_softmax_kernel<<<dim3(Ss,Hh),256,0,stream>>>(scr, c2pb, p2cb, cidx, pidx,
                                                        madd + (long)b*Ss);
      // ctx = probs @ V, written into [S, H*DH] slab of batch b
      gemm_f32_kernel<false><<<dim3(DHh/64,Ss/64,Hh),256,0,stream>>>(
          scr, vb + (long)b*Ss*Dd, ctxb + (long)b*Ss*Dd, Ss, DHh, Ss, Ss, Dd, Dd,
          (long)Ss*Ss, 64L, 64L);
    }

    gemm_w_kernel<0><<<gq,256,0,stream>>>(ctxb, Wo, bo, tmp, BSs, Dd, Dd, oW, ob, dflag);
    add_ln_kernel<<<BSs,256,0,stream>>>(h, tmp, ln1w, ln1b, ob, dflag);

    gemm_w_kernel<1><<<gf1,256,0,stream>>>(h,  W1, b1, ffb, BSs, Ff, Dd, oW1, ob1, dflag);
    gemm_w_kernel<0><<<gq,256,0,stream>>>(ffb, W2, b2, tmp, BSs, Dd, Ff, oW2, ob, dflag);
    add_ln_kernel<<<BSs,256,0,stream>>>(h, tmp, ln2w, ln2b, ob, dflag);
  }

  store_out_kernel<<<(BSs*Dd + 255)/256, 256, 0, stream>>>(h, d_out, dflag, BSs*Dd);
}